// Round 1
// baseline (786.888 us; speedup 1.0000x reference)
//
#include <hip/hip_runtime.h>
#include <cstdint>
#include <cstddef>

// ---------------- CSR build ----------------

__global__ __launch_bounds__(256) void count_kernel(const int* __restrict__ dst,
                                                    int* __restrict__ cnt, int E) {
  int e = blockIdx.x * 256 + threadIdx.x;
  if (e < E) atomicAdd(&cnt[dst[e]], 1);
}

__global__ __launch_bounds__(1024) void scan_kernel(const int* __restrict__ cnt,
                                                    int* __restrict__ row_ptr, int Nn) {
  __shared__ int sums[1024];
  int t = threadIdx.x;
  int CH = (Nn + 1023) >> 10;
  int lo = t * CH, hi = min(lo + CH, Nn);
  int s = 0;
  for (int i = lo; i < hi; ++i) s += cnt[i];
  sums[t] = s;
  __syncthreads();
  for (int off = 1; off < 1024; off <<= 1) {
    int v = sums[t];
    int add = (t >= off) ? sums[t - off] : 0;
    __syncthreads();
    sums[t] = v + add;
    __syncthreads();
  }
  int run = (t == 0) ? 0 : sums[t - 1];
  for (int i = lo; i < hi; ++i) { row_ptr[i] = run; run += cnt[i]; }
  if (t == 1023) row_ptr[Nn] = sums[1023];
}

__global__ __launch_bounds__(256) void dis_kernel(const int* __restrict__ cnt,
                                                  float* __restrict__ dis, int Nn) {
  int i = blockIdx.x * 256 + threadIdx.x;
  if (i < Nn) dis[i] = 1.0f / sqrtf((float)(cnt[i] + 1));  // +1: self-loop
}

__global__ __launch_bounds__(256) void fill_kernel(const int* __restrict__ src,
                                                   const int* __restrict__ dst,
                                                   const int* __restrict__ row_ptr,
                                                   int* __restrict__ cursor,
                                                   int* __restrict__ csr_src, int E) {
  int e = blockIdx.x * 256 + threadIdx.x;
  if (e < E) {
    int d = dst[e];
    int pos = atomicAdd(&cursor[d], 1);
    csr_src[row_ptr[d] + pos] = src[e];
  }
}

// ---------------- GEMM: C[M,128] = A[M,K] @ W[128,K]^T ----------------

#define MT 64
#define KC 32
#define NFEAT 128

__global__ __launch_bounds__(256)
void gemm_awt(const float* __restrict__ A, const float* __restrict__ W,
              float* __restrict__ C, int M, int K) {
  __shared__ float As[MT][KC + 1];        // natural layout, conflict-free stores
  __shared__ float Bs[KC][NFEAT + 4];     // k-major; row stride 528B = 33*16 (f4-aligned)
  int t = threadIdx.x;
  int m0 = blockIdx.x * MT;
  int tx = t & 15, ty = t >> 4;           // thread -> 4 rows x 8 cols
  float acc[4][8];
#pragma unroll
  for (int r = 0; r < 4; ++r)
#pragma unroll
    for (int c = 0; c < 8; ++c) acc[r][c] = 0.f;

  int o = t >> 1;            // B row this thread stages (0..127)
  int g = (t & 1) * 16;      // which half of the 32-wide k-chunk

  for (int kc = 0; kc < K; kc += KC) {
#pragma unroll
    for (int i = 0; i < 8; ++i) {         // A tile 64x32, coalesced along k
      int idx = t + i * 256;
      int ml = idx >> 5, kl = idx & 31;
      int m = m0 + ml; if (m >= M) m = M - 1;   // clamp (OOB rows never stored)
      As[ml][kl] = A[(size_t)m * K + kc + kl];
    }
#pragma unroll
    for (int j = 0; j < 4; ++j) {         // B tile 128x32 via float4 global loads
      int kk = g + 4 * j;
      float4 v = *(const float4*)&W[(size_t)o * K + kc + kk];
      Bs[kk][o] = v.x; Bs[kk + 1][o] = v.y; Bs[kk + 2][o] = v.z; Bs[kk + 3][o] = v.w;
    }
    __syncthreads();
#pragma unroll
    for (int k = 0; k < KC; ++k) {
      float av[4];
#pragma unroll
      for (int r = 0; r < 4; ++r) av[r] = As[ty * 4 + r][k];
      float4 b0 = *(const float4*)&Bs[k][tx * 8];
      float4 b1 = *(const float4*)&Bs[k][tx * 8 + 4];
      float bv[8] = {b0.x, b0.y, b0.z, b0.w, b1.x, b1.y, b1.z, b1.w};
#pragma unroll
      for (int r = 0; r < 4; ++r)
#pragma unroll
        for (int c = 0; c < 8; ++c) acc[r][c] = fmaf(av[r], bv[c], acc[r][c]);
    }
    __syncthreads();
  }
#pragma unroll
  for (int r = 0; r < 4; ++r) {
    int m = m0 + ty * 4 + r;
    if (m < M) {
      float4 s0 = {acc[r][0], acc[r][1], acc[r][2], acc[r][3]};
      float4 s1 = {acc[r][4], acc[r][5], acc[r][6], acc[r][7]};
      float* cp = &C[(size_t)m * NFEAT + tx * 8];
      *(float4*)cp = s0;
      *(float4*)(cp + 4) = s1;
    }
  }
}

// ---------------- Aggregation: out[i] = relu(sum_{s->i} dis[s]*dis[i]*m[s] + dis[i]^2*m[i] + b)

__global__ __launch_bounds__(128)
void agg_kernel(const float* __restrict__ m, const int* __restrict__ row_ptr,
                const int* __restrict__ csr_src, const float* __restrict__ dis,
                const float* __restrict__ bias, float* __restrict__ out) {
  int i = blockIdx.x;
  int f = threadIdx.x;
  float di = dis[i];
  float acc = di * di * m[(size_t)i * NFEAT + f];   // self-loop
  int e0 = row_ptr[i], e1 = row_ptr[i + 1];
  for (int e = e0; e < e1; ++e) {
    int s = csr_src[e];
    acc += di * dis[s] * m[(size_t)s * NFEAT + f];
  }
  acc += bias[f];
  out[(size_t)i * NFEAT + f] = fmaxf(acc, 0.f);
}

// ---------------- Prototype head ----------------
// distance = ||e||^2 - 2 e.p + ||p||^2 ; sim = log((d+1)/(d+eps));
// logits = sim @ last_w^T ; probs = softmax(logits)

#define NPROTO 50
#define NCLS 10

__global__ __launch_bounds__(256)
void proto_kernel(const float* __restrict__ emb, const float* __restrict__ proto,
                  const float* __restrict__ lastw, float* __restrict__ out_logits,
                  float* __restrict__ out_probs, float* __restrict__ out_dist, int Nn) {
  __shared__ float pT[128 * 51];     // transposed protos, stride 51 breaks bank aliasing
  __shared__ float lw[500];
  __shared__ float embS[4][128];
  __shared__ float simS[4][52];
  __shared__ float lgS[4][12];
  int t = threadIdx.x;
  for (int idx = t; idx < NPROTO * 128; idx += 256) {
    int p = idx >> 7, f = idx & 127;
    pT[f * 51 + p] = proto[idx];
  }
  for (int idx = t; idx < NCLS * NPROTO; idx += 256) lw[idx] = lastw[idx];
  __syncthreads();

  int w = t >> 6, lane = t & 63;
  int node = blockIdx.x * 4 + w;
  bool valid = node < Nn;

  // ||p||^2 per lane (per-block redundant compute, tiny)
  float pn = 0.f;
  if (lane < NPROTO) {
#pragma unroll 4
    for (int f = 0; f < 128; ++f) { float v = pT[f * 51 + lane]; pn += v * v; }
  }

  float e0 = 0.f, e1 = 0.f;
  if (valid) {
    e0 = emb[(size_t)node * 128 + lane];
    e1 = emb[(size_t)node * 128 + 64 + lane];
  }
  embS[w][lane] = e0;
  embS[w][64 + lane] = e1;
  float en = e0 * e0 + e1 * e1;
#pragma unroll
  for (int off = 32; off; off >>= 1) en += __shfl_down(en, off);
  en = __shfl(en, 0);
  __syncthreads();

  if (lane < NPROTO) {
    float dot = 0.f;
#pragma unroll 4
    for (int f = 0; f < 128; ++f) dot += embS[w][f] * pT[f * 51 + lane];
    float d = en - 2.f * dot + pn;
    float sim = logf((d + 1.0f) / (d + 1e-4f));
    simS[w][lane] = sim;
    if (valid) out_dist[(size_t)node * NPROTO + lane] = d;
  }
  __syncthreads();

  if (lane < NCLS) {
    float lg = 0.f;
#pragma unroll
    for (int p = 0; p < NPROTO; ++p) lg += simS[w][p] * lw[lane * NPROTO + p];
    lgS[w][lane] = lg;
  }
  __syncthreads();

  if (lane < NCLS && valid) {
    float mx = -1e30f;
#pragma unroll
    for (int c = 0; c < NCLS; ++c) mx = fmaxf(mx, lgS[w][c]);
    float ss = 0.f;
#pragma unroll
    for (int c = 0; c < NCLS; ++c) ss += expf(lgS[w][c] - mx);
    float lg = lgS[w][lane];
    out_logits[(size_t)node * NCLS + lane] = lg;
    out_probs[(size_t)node * NCLS + lane] = expf(lg - mx) / ss;
  }
}

// ---------------- launcher ----------------

extern "C" void kernel_launch(void* const* d_in, const int* in_sizes, int n_in,
                              void* d_out, int out_size, void* d_ws, size_t ws_size,
                              hipStream_t stream) {
  const float* x    = (const float*)d_in[0];
  const int*  eidx  = (const int*)d_in[1];
  const float* W1   = (const float*)d_in[2];
  const float* b1   = (const float*)d_in[3];
  const float* W2   = (const float*)d_in[4];
  const float* b2   = (const float*)d_in[5];
  const float* W3   = (const float*)d_in[6];
  const float* b3   = (const float*)d_in[7];
  const float* prot = (const float*)d_in[8];
  const float* lastw= (const float*)d_in[9];

  const int Nn = in_sizes[0] / 512;       // 50000
  const int E  = in_sizes[1] / 2;         // 640000
  const int* esrc = eidx;
  const int* edst = eidx + E;

  float* out        = (float*)d_out;
  float* out_logits = out;
  float* out_probs  = out + (size_t)Nn * NCLS;
  float* out_emb    = out + (size_t)Nn * 2 * NCLS;
  float* out_dist   = out_emb + (size_t)Nn * NFEAT;

  // workspace layout
  float* bufA = (float*)d_ws;                       // N*128
  float* bufB = bufA + (size_t)Nn * NFEAT;          // N*128
  int* cnt     = (int*)(bufB + (size_t)Nn * NFEAT); // N
  float* dis   = (float*)(cnt + Nn);                // N
  int* row_ptr = (int*)(dis + Nn);                  // N+1
  int* cursor  = row_ptr + Nn + 1;                  // N
  int* csr_src = cursor + Nn;                       // E

  hipMemsetAsync(cnt, 0, Nn * sizeof(int), stream);
  hipMemsetAsync(cursor, 0, Nn * sizeof(int), stream);
  count_kernel<<<(E + 255) / 256, 256, 0, stream>>>(edst, cnt, E);
  scan_kernel<<<1, 1024, 0, stream>>>(cnt, row_ptr, Nn);
  dis_kernel<<<(Nn + 255) / 256, 256, 0, stream>>>(cnt, dis, Nn);
  fill_kernel<<<(E + 255) / 256, 256, 0, stream>>>(esrc, edst, row_ptr, cursor, csr_src, E);

  // layer 1: m = x @ W1^T ; h1 = relu(agg + b1)
  gemm_awt<<<(Nn + MT - 1) / MT, 256, 0, stream>>>(x, W1, bufA, Nn, 512);
  agg_kernel<<<Nn, 128, 0, stream>>>(bufA, row_ptr, csr_src, dis, b1, bufB);
  // layer 2
  gemm_awt<<<(Nn + MT - 1) / MT, 256, 0, stream>>>(bufB, W2, bufA, Nn, 128);
  agg_kernel<<<Nn, 128, 0, stream>>>(bufA, row_ptr, csr_src, dis, b2, bufB);
  // layer 3 -> emb directly into d_out
  gemm_awt<<<(Nn + MT - 1) / MT, 256, 0, stream>>>(bufB, W3, bufA, Nn, 128);
  agg_kernel<<<Nn, 128, 0, stream>>>(bufA, row_ptr, csr_src, dis, b3, out_emb);

  proto_kernel<<<(Nn + 3) / 4, 256, 0, stream>>>(out_emb, prot, lastw,
                                                 out_logits, out_probs, out_dist, Nn);
}

// Round 2
// 730.743 us; speedup vs baseline: 1.0768x; 1.0768x over previous
//
#include <hip/hip_runtime.h>
#include <cstdint>
#include <cstddef>

#define NFEAT 128
#define NPROTO 50
#define NCLS 10

typedef __attribute__((ext_vector_type(8))) short short8;    // 8 x bf16
typedef __attribute__((ext_vector_type(4))) float floatx4;

// ---------------- CSR build ----------------

__global__ __launch_bounds__(256) void count_kernel(const int* __restrict__ dst,
                                                    int* __restrict__ cnt, int E) {
  int e = blockIdx.x * 256 + threadIdx.x;
  if (e < E) atomicAdd(&cnt[dst[e]], 1);
}

__global__ __launch_bounds__(1024) void scan_kernel(const int* __restrict__ cnt,
                                                    int* __restrict__ row_ptr, int Nn) {
  __shared__ int sums[1024];
  int t = threadIdx.x;
  int CH = (Nn + 1023) >> 10;
  int lo = t * CH, hi = min(lo + CH, Nn);
  int s = 0;
  for (int i = lo; i < hi; ++i) s += cnt[i];
  sums[t] = s;
  __syncthreads();
  for (int off = 1; off < 1024; off <<= 1) {
    int v = sums[t];
    int add = (t >= off) ? sums[t - off] : 0;
    __syncthreads();
    sums[t] = v + add;
    __syncthreads();
  }
  int run = (t == 0) ? 0 : sums[t - 1];
  for (int i = lo; i < hi; ++i) { row_ptr[i] = run; run += cnt[i]; }
  if (t == 1023) row_ptr[Nn] = sums[1023];
}

__global__ __launch_bounds__(256) void dis_kernel(const int* __restrict__ cnt,
                                                  float* __restrict__ dis, int Nn) {
  int i = blockIdx.x * 256 + threadIdx.x;
  if (i < Nn) dis[i] = 1.0f / sqrtf((float)(cnt[i] + 1));  // +1: self-loop
}

__global__ __launch_bounds__(256) void fill_kernel(const int* __restrict__ src,
                                                   const int* __restrict__ dst,
                                                   const int* __restrict__ row_ptr,
                                                   int* __restrict__ cursor,
                                                   int* __restrict__ csr_src, int E) {
  int e = blockIdx.x * 256 + threadIdx.x;
  if (e < E) {
    int d = dst[e];
    int pos = atomicAdd(&cursor[d], 1);
    csr_src[row_ptr[d] + pos] = src[e];
  }
}

// ---------------- weight split fp32 -> bf16 hi/lo ----------------

__device__ __forceinline__ void split1(float v, unsigned short& h, unsigned short& l) {
  unsigned int b = __float_as_uint(v);
  h = (unsigned short)(b >> 16);
  float r = v - __uint_as_float(b & 0xFFFF0000u);
  l = (unsigned short)(__float_as_uint(r) >> 16);
}

__global__ __launch_bounds__(256) void wconv_kernel(const float* __restrict__ W,
                                                    unsigned short* __restrict__ Wh,
                                                    unsigned short* __restrict__ Wl, int n) {
  int i = blockIdx.x * 256 + threadIdx.x;
  if (i < n) {
    unsigned short h, l;
    split1(W[i], h, l);
    Wh[i] = h; Wl[i] = l;
  }
}

// ---------------- MFMA GEMM: C[M,128] = A[M,K] @ W[128,K]^T ----------------
// MODE 0: A is fp32, rows scaled by dis[] and split to bf16 hi/lo in-register.
// MODE 1: A is pre-split bf16 hi/lo (already scaled).
// Split precision: 3 MFMA products (AhWh + AlWh + AhWl), rel err ~2^-17.
// Fragments (gfx950 16x16x32): A/B lane = 16*quad + idx, 8 contiguous k.
// C/D: col = lane&15, row = quad*4 + reg.

template<int MODE>
__global__ __launch_bounds__(256)
void gemm_mfma(const float* __restrict__ Af32,
               const unsigned short* __restrict__ Ah, const unsigned short* __restrict__ Al,
               const float* __restrict__ dis,
               const unsigned short* __restrict__ Wh, const unsigned short* __restrict__ Wl,
               float* __restrict__ C, int M, int K) {
  int t = threadIdx.x;
  int wv = t >> 6, lane = t & 63;
  int col = lane & 15, quad = lane >> 4;
  int m0 = blockIdx.x * 128 + wv * 32;       // each wave: 32 rows (2 m-tiles) x 128 cols

  floatx4 acc[2][8];
#pragma unroll
  for (int a = 0; a < 2; ++a)
#pragma unroll
    for (int b = 0; b < 8; ++b) acc[a][b] = floatx4{0.f, 0.f, 0.f, 0.f};

  int row0 = m0 + col, row1 = m0 + 16 + col;
  int r0 = row0 < M ? row0 : M - 1;
  int r1 = row1 < M ? row1 : M - 1;
  float d0 = 0.f, d1 = 0.f;
  if (MODE == 0) { d0 = dis[r0]; d1 = dis[r1]; }

  const size_t wb = (size_t)col * K + quad * 8;   // W base for this lane

  for (int kc = 0; kc < K; kc += 32) {
    short8 a0h, a0l, a1h, a1l;
    if (MODE == 0) {
      const float* p0 = Af32 + (size_t)r0 * K + kc + quad * 8;
      const float* p1 = Af32 + (size_t)r1 * K + kc + quad * 8;
      float4 v00 = *(const float4*)p0, v01 = *(const float4*)(p0 + 4);
      float4 v10 = *(const float4*)p1, v11 = *(const float4*)(p1 + 4);
      float f0[8] = {v00.x, v00.y, v00.z, v00.w, v01.x, v01.y, v01.z, v01.w};
      float f1[8] = {v10.x, v10.y, v10.z, v10.w, v11.x, v11.y, v11.z, v11.w};
#pragma unroll
      for (int j = 0; j < 8; ++j) {
        unsigned short h, l;
        split1(f0[j] * d0, h, l); a0h[j] = (short)h; a0l[j] = (short)l;
        split1(f1[j] * d1, h, l); a1h[j] = (short)h; a1l[j] = (short)l;
      }
    } else {
      a0h = *(const short8*)(Ah + (size_t)r0 * K + kc + quad * 8);
      a0l = *(const short8*)(Al + (size_t)r0 * K + kc + quad * 8);
      a1h = *(const short8*)(Ah + (size_t)r1 * K + kc + quad * 8);
      a1l = *(const short8*)(Al + (size_t)r1 * K + kc + quad * 8);
    }
#pragma unroll
    for (int nt = 0; nt < 8; ++nt) {
      size_t wo = wb + (size_t)nt * 16 * K + kc;
      short8 bh = *(const short8*)(Wh + wo);
      short8 bl = *(const short8*)(Wl + wo);
      acc[0][nt] = __builtin_amdgcn_mfma_f32_16x16x32_bf16(a0h, bh, acc[0][nt], 0, 0, 0);
      acc[0][nt] = __builtin_amdgcn_mfma_f32_16x16x32_bf16(a0l, bh, acc[0][nt], 0, 0, 0);
      acc[0][nt] = __builtin_amdgcn_mfma_f32_16x16x32_bf16(a0h, bl, acc[0][nt], 0, 0, 0);
      acc[1][nt] = __builtin_amdgcn_mfma_f32_16x16x32_bf16(a1h, bh, acc[1][nt], 0, 0, 0);
      acc[1][nt] = __builtin_amdgcn_mfma_f32_16x16x32_bf16(a1l, bh, acc[1][nt], 0, 0, 0);
      acc[1][nt] = __builtin_amdgcn_mfma_f32_16x16x32_bf16(a1h, bl, acc[1][nt], 0, 0, 0);
    }
  }

#pragma unroll
  for (int mt = 0; mt < 2; ++mt)
#pragma unroll
    for (int r = 0; r < 4; ++r) {
      int m = m0 + mt * 16 + quad * 4 + r;
      if (m < M) {
#pragma unroll
        for (int nt = 0; nt < 8; ++nt)
          C[(size_t)m * NFEAT + nt * 16 + col] = acc[mt][nt][r];
      }
    }
}

// ---------------- Aggregation ----------------
// m rows already carry dis[src]; out[i] = relu(dis[i]*(sum_{s->i} m[s] + m[i]) + b).
// MODE 0: write next-layer input = dis[i]*out as bf16 hi/lo (pre-scaled, pre-split).
// MODE 1: write out as fp32 (final embedding).

template<int MODE>
__global__ __launch_bounds__(256)
void agg_kernel(const float* __restrict__ m, const int* __restrict__ row_ptr,
                const int* __restrict__ csr_src, const float* __restrict__ dis,
                const float* __restrict__ bias,
                unsigned int* __restrict__ out_h, unsigned int* __restrict__ out_l,
                float* __restrict__ out_f, int Nn) {
  int w = threadIdx.x >> 6, lane = threadIdx.x & 63;
  int i = blockIdx.x * 4 + w;
  if (i >= Nn) return;
  const float2* m2 = (const float2*)m;
  float2 acc = m2[(size_t)i * 64 + lane];          // self-loop term
  int e0 = row_ptr[i], e1 = row_ptr[i + 1];
  for (int e = e0; e < e1; ++e) {
    int s = csr_src[e];
    float2 v = m2[(size_t)s * 64 + lane];
    acc.x += v.x; acc.y += v.y;
  }
  float di = dis[i];
  float2 b = ((const float2*)bias)[lane];
  float rx = fmaxf(fmaf(di, acc.x, b.x), 0.f);
  float ry = fmaxf(fmaf(di, acc.y, b.y), 0.f);
  if (MODE == 0) {
    float sx = di * rx, sy = di * ry;              // pre-scale for next layer
    unsigned short hx, lx, hy, ly;
    split1(sx, hx, lx);
    split1(sy, hy, ly);
    out_h[(size_t)i * 64 + lane] = (unsigned int)hx | ((unsigned int)hy << 16);
    out_l[(size_t)i * 64 + lane] = (unsigned int)lx | ((unsigned int)ly << 16);
  } else {
    ((float2*)out_f)[(size_t)i * 64 + lane] = make_float2(rx, ry);
  }
}

// ---------------- Prototype head (grid-stride, staging amortized) ----------------

__global__ __launch_bounds__(256)
void proto_kernel(const float* __restrict__ emb, const float* __restrict__ proto,
                  const float* __restrict__ lastw, float* __restrict__ out_logits,
                  float* __restrict__ out_probs, float* __restrict__ out_dist, int Nn) {
  __shared__ float pT[128 * 51];     // transposed protos, stride 51 breaks bank aliasing
  __shared__ float lw[NCLS * NPROTO];
  __shared__ float embS[4][128];
  __shared__ float simS[4][52];
  __shared__ float lgS[4][12];
  int t = threadIdx.x;
  for (int idx = t; idx < NPROTO * 128; idx += 256) {
    int p = idx >> 7, f = idx & 127;
    pT[f * 51 + p] = proto[idx];
  }
  for (int idx = t; idx < NCLS * NPROTO; idx += 256) lw[idx] = lastw[idx];
  __syncthreads();

  int w = t >> 6, lane = t & 63;

  float pn = 0.f;                    // ||p||^2, once per block
  if (lane < NPROTO) {
#pragma unroll 4
    for (int f = 0; f < 128; ++f) { float v = pT[f * 51 + lane]; pn += v * v; }
  }

  int ngroups = (Nn + 3) >> 2;
  int iters = (ngroups + gridDim.x - 1) / gridDim.x;
  for (int it = 0; it < iters; ++it) {
    int g = blockIdx.x + it * gridDim.x;
    int node = g * 4 + w;
    bool valid = (g < ngroups) && (node < Nn);
    float e0 = 0.f, e1 = 0.f;
    if (valid) {
      e0 = emb[(size_t)node * 128 + lane];
      e1 = emb[(size_t)node * 128 + 64 + lane];
    }
    embS[w][lane] = e0;
    embS[w][64 + lane] = e1;
    float en = e0 * e0 + e1 * e1;
#pragma unroll
    for (int off = 32; off; off >>= 1) en += __shfl_down(en, off);
    en = __shfl(en, 0);
    __syncthreads();

    if (lane < NPROTO) {
      float dot = 0.f;
#pragma unroll 4
      for (int f = 0; f < 128; ++f) dot += embS[w][f] * pT[f * 51 + lane];
      float d = en - 2.f * dot + pn;
      simS[w][lane] = logf((d + 1.0f) / (d + 1e-4f));
      if (valid) out_dist[(size_t)node * NPROTO + lane] = d;
    }
    __syncthreads();

    if (lane < NCLS) {
      float lg = 0.f;
#pragma unroll
      for (int p = 0; p < NPROTO; ++p) lg += simS[w][p] * lw[lane * NPROTO + p];
      lgS[w][lane] = lg;
    }
    __syncthreads();

    if (lane < NCLS && valid) {
      float mx = -1e30f;
#pragma unroll
      for (int c = 0; c < NCLS; ++c) mx = fmaxf(mx, lgS[w][c]);
      float ss = 0.f;
#pragma unroll
      for (int c = 0; c < NCLS; ++c) ss += expf(lgS[w][c] - mx);
      float lg = lgS[w][lane];
      out_logits[(size_t)node * NCLS + lane] = lg;
      out_probs[(size_t)node * NCLS + lane] = expf(lg - mx) / ss;
    }
    __syncthreads();   // protect shared reuse next iteration
  }
}

// ---------------- launcher ----------------

extern "C" void kernel_launch(void* const* d_in, const int* in_sizes, int n_in,
                              void* d_out, int out_size, void* d_ws, size_t ws_size,
                              hipStream_t stream) {
  const float* x    = (const float*)d_in[0];
  const int*  eidx  = (const int*)d_in[1];
  const float* W1   = (const float*)d_in[2];
  const float* b1   = (const float*)d_in[3];
  const float* W2   = (const float*)d_in[4];
  const float* b2   = (const float*)d_in[5];
  const float* W3   = (const float*)d_in[6];
  const float* b3   = (const float*)d_in[7];
  const float* prot = (const float*)d_in[8];
  const float* lastw= (const float*)d_in[9];

  const int Nn = in_sizes[0] / 512;       // 50000
  const int E  = in_sizes[1] / 2;         // 640000
  const int K1 = 512;
  const int* esrc = eidx;
  const int* edst = eidx + E;

  float* out        = (float*)d_out;
  float* out_logits = out;
  float* out_probs  = out + (size_t)Nn * NCLS;
  float* out_emb    = out + (size_t)Nn * 2 * NCLS;
  float* out_dist   = out_emb + (size_t)Nn * NFEAT;

  // workspace layout
  float* mbuf  = (float*)d_ws;                              // N*128 fp32
  unsigned int* hh = (unsigned int*)(mbuf + (size_t)Nn * NFEAT);   // N*64 uints (N*128 bf16)
  unsigned int* hl = hh + (size_t)Nn * 64;
  unsigned short* W1h = (unsigned short*)(hl + (size_t)Nn * 64);   // 128*512
  unsigned short* W1l = W1h + 128 * 512;
  unsigned short* W2h = W1l + 128 * 512;                            // 128*128
  unsigned short* W2l = W2h + 128 * 128;
  unsigned short* W3h = W2l + 128 * 128;
  unsigned short* W3l = W3h + 128 * 128;
  int* cnt     = (int*)(W3l + 128 * 128);                   // N
  float* dis   = (float*)(cnt + Nn);                        // N
  int* row_ptr = (int*)(dis + Nn);                          // N+1
  int* cursor  = row_ptr + Nn + 1;                          // N
  int* csr_src = cursor + Nn;                               // E

  hipMemsetAsync(cnt, 0, Nn * sizeof(int), stream);
  hipMemsetAsync(cursor, 0, Nn * sizeof(int), stream);
  count_kernel<<<(E + 255) / 256, 256, 0, stream>>>(edst, cnt, E);
  scan_kernel<<<1, 1024, 0, stream>>>(cnt, row_ptr, Nn);
  dis_kernel<<<(Nn + 255) / 256, 256, 0, stream>>>(cnt, dis, Nn);
  fill_kernel<<<(E + 255) / 256, 256, 0, stream>>>(esrc, edst, row_ptr, cursor, csr_src, E);

  wconv_kernel<<<(128 * 512 + 255) / 256, 256, 0, stream>>>(W1, W1h, W1l, 128 * 512);
  wconv_kernel<<<(128 * 128 + 255) / 256, 256, 0, stream>>>(W2, W2h, W2l, 128 * 128);
  wconv_kernel<<<(128 * 128 + 255) / 256, 256, 0, stream>>>(W3, W3h, W3l, 128 * 128);

  int gblocks = (Nn + 127) / 128;
  // layer 1: m = (dis . x) @ W1^T  (fp32 input, in-register split)
  gemm_mfma<0><<<gblocks, 256, 0, stream>>>(x, nullptr, nullptr, dis, W1h, W1l, mbuf, Nn, K1);
  agg_kernel<0><<<(Nn + 3) / 4, 256, 0, stream>>>(mbuf, row_ptr, csr_src, dis, b1, hh, hl, nullptr, Nn);
  // layer 2 (bf16 hi/lo input, already scaled)
  gemm_mfma<1><<<gblocks, 256, 0, stream>>>(nullptr, (const unsigned short*)hh,
                                            (const unsigned short*)hl, dis, W2h, W2l, mbuf, Nn, NFEAT);
  agg_kernel<0><<<(Nn + 3) / 4, 256, 0, stream>>>(mbuf, row_ptr, csr_src, dis, b2, hh, hl, nullptr, Nn);
  // layer 3 -> emb fp32 into d_out
  gemm_mfma<1><<<gblocks, 256, 0, stream>>>(nullptr, (const unsigned short*)hh,
                                            (const unsigned short*)hl, dis, W3h, W3l, mbuf, Nn, NFEAT);
  agg_kernel<1><<<(Nn + 3) / 4, 256, 0, stream>>>(mbuf, row_ptr, csr_src, dis, b3, nullptr, nullptr, out_emb, Nn);

  proto_kernel<<<512, 256, 0, stream>>>(out_emb, prot, lastw, out_logits, out_probs, out_dist, Nn);
}

// Round 3
// 619.315 us; speedup vs baseline: 1.2706x; 1.1799x over previous
//
#include <hip/hip_runtime.h>
#include <cstdint>
#include <cstddef>

#define NFEAT 128
#define NPROTO 50
#define NCLS 10

typedef __attribute__((ext_vector_type(8))) short short8;    // 8 x bf16
typedef __attribute__((ext_vector_type(4))) float floatx4;

// ---------------- CSR build ----------------

__global__ __launch_bounds__(256) void count_kernel(const int* __restrict__ dst,
                                                    int* __restrict__ cnt, int E) {
  int e = blockIdx.x * 256 + threadIdx.x;
  if (e < E) atomicAdd(&cnt[dst[e]], 1);
}

__global__ __launch_bounds__(1024) void scan_kernel(const int* __restrict__ cnt,
                                                    int* __restrict__ row_ptr, int Nn) {
  __shared__ int sums[1024];
  int t = threadIdx.x;
  int CH = (Nn + 1023) >> 10;
  int lo = t * CH, hi = min(lo + CH, Nn);
  int s = 0;
  for (int i = lo; i < hi; ++i) s += cnt[i];
  sums[t] = s;
  __syncthreads();
  for (int off = 1; off < 1024; off <<= 1) {
    int v = sums[t];
    int add = (t >= off) ? sums[t - off] : 0;
    __syncthreads();
    sums[t] = v + add;
    __syncthreads();
  }
  int run = (t == 0) ? 0 : sums[t - 1];
  for (int i = lo; i < hi; ++i) { row_ptr[i] = run; run += cnt[i]; }
  if (t == 1023) row_ptr[Nn] = sums[1023];
}

__global__ __launch_bounds__(256) void dis_kernel(const int* __restrict__ cnt,
                                                  float* __restrict__ dis, int Nn) {
  int i = blockIdx.x * 256 + threadIdx.x;
  if (i < Nn) dis[i] = 1.0f / sqrtf((float)(cnt[i] + 1));  // +1: self-loop
}

__global__ __launch_bounds__(256) void fill_kernel(const int* __restrict__ src,
                                                   const int* __restrict__ dst,
                                                   const int* __restrict__ row_ptr,
                                                   int* __restrict__ cursor,
                                                   int* __restrict__ csr_src, int E) {
  int e = blockIdx.x * 256 + threadIdx.x;
  if (e < E) {
    int d = dst[e];
    int pos = atomicAdd(&cursor[d], 1);
    csr_src[row_ptr[d] + pos] = src[e];
  }
}

// ---------------- fp32 -> bf16 hi/lo split ----------------

__device__ __forceinline__ void split1(float v, unsigned short& h, unsigned short& l) {
  unsigned int b = __float_as_uint(v);
  h = (unsigned short)(b >> 16);
  float r = v - __uint_as_float(b & 0xFFFF0000u);
  l = (unsigned short)(__float_as_uint(r) >> 16);
}

__global__ __launch_bounds__(256) void wconv_kernel(const float* __restrict__ W,
                                                    unsigned short* __restrict__ Wh,
                                                    unsigned short* __restrict__ Wl, int n) {
  int i = blockIdx.x * 256 + threadIdx.x;
  if (i < n) {
    unsigned short h, l;
    split1(W[i], h, l);
    Wh[i] = h; Wl[i] = l;
  }
}

// protos: split to bf16 hi/lo padded to 64 rows, plus squared norms
__global__ __launch_bounds__(128)
void psplit_kernel(const float* __restrict__ proto, unsigned short* __restrict__ Ph,
                   unsigned short* __restrict__ Pl, float* __restrict__ pn) {
  int t = threadIdx.x;
  for (int idx = t; idx < 64 * 128; idx += 128) {
    int p = idx >> 7;
    float v = (p < NPROTO) ? proto[p * 128 + (idx & 127)] : 0.f;
    unsigned short h, l;
    split1(v, h, l);
    Ph[idx] = h; Pl[idx] = l;
  }
  if (t < 64) {
    float s = 0.f;
    if (t < NPROTO)
      for (int f = 0; f < 128; ++f) { float v = proto[t * 128 + f]; s += v * v; }
    pn[t] = s;
  }
}

// ---------------- MFMA GEMM: C[M,128] = A[M,K] @ W[128,K]^T ----------------
// MODE 0: A fp32, rows scaled by dis[], split to bf16 hi/lo in-register.
// MODE 1: A pre-split bf16 hi/lo (already scaled).
// 3 MFMA products (AhWh + AlWh + AhWl), rel err ~2^-17.

template<int MODE>
__global__ __launch_bounds__(256)
void gemm_mfma(const float* __restrict__ Af32,
               const unsigned short* __restrict__ Ah, const unsigned short* __restrict__ Al,
               const float* __restrict__ dis,
               const unsigned short* __restrict__ Wh, const unsigned short* __restrict__ Wl,
               float* __restrict__ C, int M, int K) {
  int t = threadIdx.x;
  int wv = t >> 6, lane = t & 63;
  int col = lane & 15, quad = lane >> 4;
  int m0 = blockIdx.x * 128 + wv * 32;       // each wave: 32 rows x 128 cols

  floatx4 acc[2][8];
#pragma unroll
  for (int a = 0; a < 2; ++a)
#pragma unroll
    for (int b = 0; b < 8; ++b) acc[a][b] = floatx4{0.f, 0.f, 0.f, 0.f};

  int row0 = m0 + col, row1 = m0 + 16 + col;
  int r0 = row0 < M ? row0 : M - 1;
  int r1 = row1 < M ? row1 : M - 1;
  float d0 = 0.f, d1 = 0.f;
  if (MODE == 0) { d0 = dis[r0]; d1 = dis[r1]; }

  const size_t wb = (size_t)col * K + quad * 8;

  for (int kc = 0; kc < K; kc += 32) {
    short8 a0h, a0l, a1h, a1l;
    if (MODE == 0) {
      const float* p0 = Af32 + (size_t)r0 * K + kc + quad * 8;
      const float* p1 = Af32 + (size_t)r1 * K + kc + quad * 8;
      float4 v00 = *(const float4*)p0, v01 = *(const float4*)(p0 + 4);
      float4 v10 = *(const float4*)p1, v11 = *(const float4*)(p1 + 4);
      float f0[8] = {v00.x, v00.y, v00.z, v00.w, v01.x, v01.y, v01.z, v01.w};
      float f1[8] = {v10.x, v10.y, v10.z, v10.w, v11.x, v11.y, v11.z, v11.w};
#pragma unroll
      for (int j = 0; j < 8; ++j) {
        unsigned short h, l;
        split1(f0[j] * d0, h, l); a0h[j] = (short)h; a0l[j] = (short)l;
        split1(f1[j] * d1, h, l); a1h[j] = (short)h; a1l[j] = (short)l;
      }
    } else {
      a0h = *(const short8*)(Ah + (size_t)r0 * K + kc + quad * 8);
      a0l = *(const short8*)(Al + (size_t)r0 * K + kc + quad * 8);
      a1h = *(const short8*)(Ah + (size_t)r1 * K + kc + quad * 8);
      a1l = *(const short8*)(Al + (size_t)r1 * K + kc + quad * 8);
    }
#pragma unroll
    for (int nt = 0; nt < 8; ++nt) {
      size_t wo = wb + (size_t)nt * 16 * K + kc;
      short8 bh = *(const short8*)(Wh + wo);
      short8 bl = *(const short8*)(Wl + wo);
      acc[0][nt] = __builtin_amdgcn_mfma_f32_16x16x32_bf16(a0h, bh, acc[0][nt], 0, 0, 0);
      acc[0][nt] = __builtin_amdgcn_mfma_f32_16x16x32_bf16(a0l, bh, acc[0][nt], 0, 0, 0);
      acc[0][nt] = __builtin_amdgcn_mfma_f32_16x16x32_bf16(a0h, bl, acc[0][nt], 0, 0, 0);
      acc[1][nt] = __builtin_amdgcn_mfma_f32_16x16x32_bf16(a1h, bh, acc[1][nt], 0, 0, 0);
      acc[1][nt] = __builtin_amdgcn_mfma_f32_16x16x32_bf16(a1l, bh, acc[1][nt], 0, 0, 0);
      acc[1][nt] = __builtin_amdgcn_mfma_f32_16x16x32_bf16(a1h, bl, acc[1][nt], 0, 0, 0);
    }
  }

#pragma unroll
  for (int mt = 0; mt < 2; ++mt)
#pragma unroll
    for (int r = 0; r < 4; ++r) {
      int m = m0 + mt * 16 + quad * 4 + r;
      if (m < M) {
#pragma unroll
        for (int nt = 0; nt < 8; ++nt)
          C[(size_t)m * NFEAT + nt * 16 + col] = acc[mt][nt][r];
      }
    }
}

// ---------------- Aggregation ----------------
// m rows already carry dis[src]; out[i] = relu(dis[i]*(sum_{s->i} m[s] + m[i]) + b).
// MODE 0: write next-layer input = dis[i]*out as bf16 hi/lo.  MODE 1: fp32 out.

template<int MODE>
__global__ __launch_bounds__(256)
void agg_kernel(const float* __restrict__ m, const int* __restrict__ row_ptr,
                const int* __restrict__ csr_src, const float* __restrict__ dis,
                const float* __restrict__ bias,
                unsigned int* __restrict__ out_h, unsigned int* __restrict__ out_l,
                float* __restrict__ out_f, int Nn) {
  int w = threadIdx.x >> 6, lane = threadIdx.x & 63;
  int i = blockIdx.x * 4 + w;
  if (i >= Nn) return;
  const float2* m2 = (const float2*)m;
  float2 acc = m2[(size_t)i * 64 + lane];          // self-loop term
  int e0 = row_ptr[i], e1 = row_ptr[i + 1];
  int e = e0;
  for (; e + 4 <= e1; e += 4) {                    // 4 independent gathers in flight
    int s0 = csr_src[e], s1 = csr_src[e + 1], s2 = csr_src[e + 2], s3 = csr_src[e + 3];
    float2 v0 = m2[(size_t)s0 * 64 + lane];
    float2 v1 = m2[(size_t)s1 * 64 + lane];
    float2 v2 = m2[(size_t)s2 * 64 + lane];
    float2 v3 = m2[(size_t)s3 * 64 + lane];
    acc.x += (v0.x + v1.x) + (v2.x + v3.x);
    acc.y += (v0.y + v1.y) + (v2.y + v3.y);
  }
  for (; e < e1; ++e) {
    int s = csr_src[e];
    float2 v = m2[(size_t)s * 64 + lane];
    acc.x += v.x; acc.y += v.y;
  }
  float di = dis[i];
  float2 b = ((const float2*)bias)[lane];
  float rx = fmaxf(fmaf(di, acc.x, b.x), 0.f);
  float ry = fmaxf(fmaf(di, acc.y, b.y), 0.f);
  if (MODE == 0) {
    float sx = di * rx, sy = di * ry;              // pre-scale for next layer
    unsigned short hx, lx, hy, ly;
    split1(sx, hx, lx);
    split1(sy, hy, ly);
    out_h[(size_t)i * 64 + lane] = (unsigned int)hx | ((unsigned int)hy << 16);
    out_l[(size_t)i * 64 + lane] = (unsigned int)lx | ((unsigned int)ly << 16);
  } else {
    ((float2*)out_f)[(size_t)i * 64 + lane] = make_float2(rx, ry);
  }
}

// ---------------- Prototype head via MFMA ----------------
// Per wave: 16 nodes x 64 proto-slots (50 real). xp via split-bf16 MFMA;
// ||e||^2 exact fp32 from A-fragments (quad shuffle-reduce); dist/sim in
// C-layout regs; sim -> LDS (stride 65, conflict-free) -> per-node logits+softmax.

__global__ __launch_bounds__(256)
void proto_mfma(const float* __restrict__ emb,
                const unsigned short* __restrict__ Ph, const unsigned short* __restrict__ Pl,
                const float* __restrict__ pn, const float* __restrict__ lastw,
                float* __restrict__ out_logits, float* __restrict__ out_probs,
                float* __restrict__ out_dist, int Nn) {
  __shared__ float simS[64][65];
  int t = threadIdx.x;
  int w = t >> 6, lane = t & 63;
  int col = lane & 15, quad = lane >> 4;
  int m0 = blockIdx.x * 64 + w * 16;
  int row = m0 + col;
  int r0 = row < Nn ? row : Nn - 1;

  floatx4 acc[4];
#pragma unroll
  for (int nt = 0; nt < 4; ++nt) acc[nt] = floatx4{0.f, 0.f, 0.f, 0.f};

  float en = 0.f;
  const float* ap = emb + (size_t)r0 * 128 + quad * 8;
#pragma unroll
  for (int kc = 0; kc < 4; ++kc) {
    float4 va = *(const float4*)(ap + kc * 32);
    float4 vb = *(const float4*)(ap + kc * 32 + 4);
    float f[8] = {va.x, va.y, va.z, va.w, vb.x, vb.y, vb.z, vb.w};
    short8 ah, al;
#pragma unroll
    for (int j = 0; j < 8; ++j) {
      unsigned short h, l;
      split1(f[j], h, l);
      ah[j] = (short)h; al[j] = (short)l;
      en = fmaf(f[j], f[j], en);
    }
#pragma unroll
    for (int nt = 0; nt < 4; ++nt) {
      const unsigned short* bp = Ph + (size_t)(nt * 16 + col) * 128 + kc * 32 + quad * 8;
      const unsigned short* bq = Pl + (size_t)(nt * 16 + col) * 128 + kc * 32 + quad * 8;
      short8 bh = *(const short8*)bp;
      short8 bl = *(const short8*)bq;
      acc[nt] = __builtin_amdgcn_mfma_f32_16x16x32_bf16(ah, bh, acc[nt], 0, 0, 0);
      acc[nt] = __builtin_amdgcn_mfma_f32_16x16x32_bf16(al, bh, acc[nt], 0, 0, 0);
      acc[nt] = __builtin_amdgcn_mfma_f32_16x16x32_bf16(ah, bl, acc[nt], 0, 0, 0);
    }
  }
  // row-norm: reduce the 4 quads holding the same row
  en += __shfl_xor(en, 16);
  en += __shfl_xor(en, 32);

  float pnv[4];
#pragma unroll
  for (int nt = 0; nt < 4; ++nt) pnv[nt] = pn[nt * 16 + col];

#pragma unroll
  for (int r = 0; r < 4; ++r) {
    int node = m0 + quad * 4 + r;
    float enr = __shfl(en, quad * 4 + r);
    bool valid = node < Nn;
#pragma unroll
    for (int nt = 0; nt < 4; ++nt) {
      int p = nt * 16 + col;
      float d = enr - 2.f * acc[nt][r] + pnv[nt];
      float sim = (p < NPROTO) ? logf((d + 1.0f) / (d + 1e-4f)) : 0.f;
      simS[w * 16 + quad * 4 + r][p] = sim;
      if (valid && p < NPROTO) out_dist[(size_t)node * NPROTO + p] = d;
    }
  }
  __syncthreads();

  if (t < 64) {
    int node = blockIdx.x * 64 + t;
    if (node < Nn) {
      float sims[NPROTO];
#pragma unroll
      for (int p = 0; p < NPROTO; ++p) sims[p] = simS[t][p];
      float lg[NCLS];
      float mx = -1e30f;
#pragma unroll
      for (int c = 0; c < NCLS; ++c) {
        float s = 0.f;
#pragma unroll
        for (int p = 0; p < NPROTO; ++p) s = fmaf(sims[p], lastw[c * NPROTO + p], s);
        lg[c] = s;
        mx = fmaxf(mx, s);
      }
      float ss = 0.f;
#pragma unroll
      for (int c = 0; c < NCLS; ++c) ss += expf(lg[c] - mx);
      float inv = 1.f / ss;
#pragma unroll
      for (int c = 0; c < NCLS; ++c) {
        out_logits[(size_t)node * NCLS + c] = lg[c];
        out_probs[(size_t)node * NCLS + c] = expf(lg[c] - mx) * inv;
      }
    }
  }
}

// ---------------- launcher ----------------

extern "C" void kernel_launch(void* const* d_in, const int* in_sizes, int n_in,
                              void* d_out, int out_size, void* d_ws, size_t ws_size,
                              hipStream_t stream) {
  const float* x    = (const float*)d_in[0];
  const int*  eidx  = (const int*)d_in[1];
  const float* W1   = (const float*)d_in[2];
  const float* b1   = (const float*)d_in[3];
  const float* W2   = (const float*)d_in[4];
  const float* b2   = (const float*)d_in[5];
  const float* W3   = (const float*)d_in[6];
  const float* b3   = (const float*)d_in[7];
  const float* prot = (const float*)d_in[8];
  const float* lastw= (const float*)d_in[9];

  const int Nn = in_sizes[0] / 512;       // 50000
  const int E  = in_sizes[1] / 2;         // 640000
  const int K1 = 512;
  const int* esrc = eidx;
  const int* edst = eidx + E;

  float* out        = (float*)d_out;
  float* out_logits = out;
  float* out_probs  = out + (size_t)Nn * NCLS;
  float* out_emb    = out + (size_t)Nn * 2 * NCLS;
  float* out_dist   = out_emb + (size_t)Nn * NFEAT;

  // workspace layout
  float* mbuf  = (float*)d_ws;                              // N*128 fp32
  unsigned int* hh = (unsigned int*)(mbuf + (size_t)Nn * NFEAT);
  unsigned int* hl = hh + (size_t)Nn * 64;
  unsigned short* W1h = (unsigned short*)(hl + (size_t)Nn * 64);   // 128*512
  unsigned short* W1l = W1h + 128 * 512;
  unsigned short* W2h = W1l + 128 * 512;                            // 128*128
  unsigned short* W2l = W2h + 128 * 128;
  unsigned short* W3h = W2l + 128 * 128;
  unsigned short* W3l = W3h + 128 * 128;
  unsigned short* Ph  = W3l + 128 * 128;                            // 64*128
  unsigned short* Pl  = Ph + 64 * 128;
  float* pn    = (float*)(Pl + 64 * 128);                   // 64
  int* cnt     = (int*)(pn + 64);                           // N
  float* dis   = (float*)(cnt + Nn);                        // N
  int* row_ptr = (int*)(dis + Nn);                          // N+1
  int* cursor  = row_ptr + Nn + 1;                          // N
  int* csr_src = cursor + Nn;                               // E

  hipMemsetAsync(cnt, 0, Nn * sizeof(int), stream);
  hipMemsetAsync(cursor, 0, Nn * sizeof(int), stream);
  count_kernel<<<(E + 255) / 256, 256, 0, stream>>>(edst, cnt, E);
  scan_kernel<<<1, 1024, 0, stream>>>(cnt, row_ptr, Nn);
  dis_kernel<<<(Nn + 255) / 256, 256, 0, stream>>>(cnt, dis, Nn);
  fill_kernel<<<(E + 255) / 256, 256, 0, stream>>>(esrc, edst, row_ptr, cursor, csr_src, E);

  wconv_kernel<<<(128 * 512 + 255) / 256, 256, 0, stream>>>(W1, W1h, W1l, 128 * 512);
  wconv_kernel<<<(128 * 128 + 255) / 256, 256, 0, stream>>>(W2, W2h, W2l, 128 * 128);
  wconv_kernel<<<(128 * 128 + 255) / 256, 256, 0, stream>>>(W3, W3h, W3l, 128 * 128);
  psplit_kernel<<<1, 128, 0, stream>>>(prot, Ph, Pl, pn);

  int gblocks = (Nn + 127) / 128;
  // layer 1: m = (dis . x) @ W1^T
  gemm_mfma<0><<<gblocks, 256, 0, stream>>>(x, nullptr, nullptr, dis, W1h, W1l, mbuf, Nn, K1);
  agg_kernel<0><<<(Nn + 3) / 4, 256, 0, stream>>>(mbuf, row_ptr, csr_src, dis, b1, hh, hl, nullptr, Nn);
  // layer 2
  gemm_mfma<1><<<gblocks, 256, 0, stream>>>(nullptr, (const unsigned short*)hh,
                                            (const unsigned short*)hl, dis, W2h, W2l, mbuf, Nn, NFEAT);
  agg_kernel<0><<<(Nn + 3) / 4, 256, 0, stream>>>(mbuf, row_ptr, csr_src, dis, b2, hh, hl, nullptr, Nn);
  // layer 3 -> emb fp32 into d_out
  gemm_mfma<1><<<gblocks, 256, 0, stream>>>(nullptr, (const unsigned short*)hh,
                                            (const unsigned short*)hl, dis, W3h, W3l, mbuf, Nn, NFEAT);
  agg_kernel<1><<<(Nn + 3) / 4, 256, 0, stream>>>(mbuf, row_ptr, csr_src, dis, b3, nullptr, nullptr, out_emb, Nn);

  proto_mfma<<<(Nn + 63) / 64, 256, 0, stream>>>(out_emb, Ph, Pl, pn, lastw,
                                                 out_logits, out_probs, out_dist, Nn);
}

// Round 4
// 603.086 us; speedup vs baseline: 1.3048x; 1.0269x over previous
//
#include <hip/hip_runtime.h>
#include <cstdint>
#include <cstddef>

#define NFEAT 128
#define NPROTO 50
#define NCLS 10

typedef __attribute__((ext_vector_type(8))) short short8;    // 8 x bf16
typedef __attribute__((ext_vector_type(4))) float floatx4;

// ---------------- CSR build ----------------

__global__ __launch_bounds__(256) void count_kernel(const int* __restrict__ dst,
                                                    int* __restrict__ cnt, int E) {
  int e = blockIdx.x * 256 + threadIdx.x;
  if (e < E) atomicAdd(&cnt[dst[e]], 1);
}

__global__ __launch_bounds__(1024) void scan_kernel(const int* __restrict__ cnt,
                                                    int* __restrict__ row_ptr, int Nn) {
  __shared__ int sums[1024];
  int t = threadIdx.x;
  int CH = (Nn + 1023) >> 10;
  int lo = t * CH, hi = min(lo + CH, Nn);
  int s = 0;
  for (int i = lo; i < hi; ++i) s += cnt[i];
  sums[t] = s;
  __syncthreads();
  for (int off = 1; off < 1024; off <<= 1) {
    int v = sums[t];
    int add = (t >= off) ? sums[t - off] : 0;
    __syncthreads();
    sums[t] = v + add;
    __syncthreads();
  }
  int run = (t == 0) ? 0 : sums[t - 1];
  for (int i = lo; i < hi; ++i) { row_ptr[i] = run; run += cnt[i]; }
  if (t == 1023) row_ptr[Nn] = sums[1023];
}

__global__ __launch_bounds__(256) void dis_kernel(const int* __restrict__ cnt,
                                                  float* __restrict__ dis, int Nn) {
  int i = blockIdx.x * 256 + threadIdx.x;
  if (i < Nn) dis[i] = 1.0f / sqrtf((float)(cnt[i] + 1));  // +1: self-loop
}

__global__ __launch_bounds__(256) void fill_kernel(const int* __restrict__ src,
                                                   const int* __restrict__ dst,
                                                   const int* __restrict__ row_ptr,
                                                   int* __restrict__ cursor,
                                                   int* __restrict__ csr_src, int E) {
  int e = blockIdx.x * 256 + threadIdx.x;
  if (e < E) {
    int d = dst[e];
    int pos = atomicAdd(&cursor[d], 1);
    csr_src[row_ptr[d] + pos] = src[e];
  }
}

// ---------------- fp32 -> bf16 hi/lo split ----------------

__device__ __forceinline__ void split1(float v, unsigned short& h, unsigned short& l) {
  unsigned int b = __float_as_uint(v);
  h = (unsigned short)(b >> 16);
  float r = v - __uint_as_float(b & 0xFFFF0000u);
  l = (unsigned short)(__float_as_uint(r) >> 16);
}

__global__ __launch_bounds__(256) void wconv_kernel(const float* __restrict__ W,
                                                    unsigned short* __restrict__ Wh,
                                                    unsigned short* __restrict__ Wl, int n) {
  int i = blockIdx.x * 256 + threadIdx.x;
  if (i < n) {
    unsigned short h, l;
    split1(W[i], h, l);
    Wh[i] = h; Wl[i] = l;
  }
}

// protos: split to bf16 hi/lo padded to 64 rows, plus squared norms
__global__ __launch_bounds__(128)
void psplit_kernel(const float* __restrict__ proto, unsigned short* __restrict__ Ph,
                   unsigned short* __restrict__ Pl, float* __restrict__ pn) {
  int t = threadIdx.x;
  for (int idx = t; idx < 64 * 128; idx += 128) {
    int p = idx >> 7;
    float v = (p < NPROTO) ? proto[p * 128 + (idx & 127)] : 0.f;
    unsigned short h, l;
    split1(v, h, l);
    Ph[idx] = h; Pl[idx] = l;
  }
  if (t < 64) {
    float s = 0.f;
    if (t < NPROTO)
      for (int f = 0; f < 128; ++f) { float v = proto[t * 128 + f]; s += v * v; }
    pn[t] = s;
  }
}

// ---------------- MFMA GEMM v2: C[M,128] = A[M,K] @ W[128,K]^T ----------------
// Block: 64 rows x 128 cols, 4 waves in 2x2 (wave = 32 rows x 64 cols).
// W k-chunk (BK=64, hi+lo = 32 KB) staged once per block into LDS via
// global_load_lds(16B), pre-arranged fragment-linear: unit(g,q,c) at
// [plane][ (g*8+q)*16 + c ], so B-fragment reads are conflict-free b128.
// A per-lane direct global loads (each A row read by exactly one block).
// MODE 0: A fp32, scaled by dis[], split in-register. MODE 1: A bf16 hi/lo.

template<int MODE>
__global__ __launch_bounds__(256)
void gemm_v2(const float* __restrict__ Af32,
             const unsigned short* __restrict__ Ah, const unsigned short* __restrict__ Al,
             const float* __restrict__ dis,
             const unsigned short* __restrict__ Wh, const unsigned short* __restrict__ Wl,
             float* __restrict__ C, int M, int K) {
  __shared__ short8 Wlds[2048];           // [2 planes][1024 units] = 32 KB
  int t = threadIdx.x;
  int w = t >> 6, lane = t & 63;
  int col = lane & 15, quad = lane >> 4;
  int wr = w >> 1, wc = w & 1;
  int m_base = blockIdx.x * 64 + wr * 32;

  floatx4 acc[2][4];
#pragma unroll
  for (int a = 0; a < 2; ++a)
#pragma unroll
    for (int b = 0; b < 4; ++b) acc[a][b] = floatx4{0.f, 0.f, 0.f, 0.f};

  int row[2];
  float dsc[2] = {0.f, 0.f};
#pragma unroll
  for (int t2 = 0; t2 < 2; ++t2) {
    int r = m_base + t2 * 16 + col;
    row[t2] = r < M ? r : M - 1;
    if (MODE == 0) dsc[t2] = dis[row[t2]];
  }

  // staging source indices (wave-invariant parts)
  const int j0 = w * 4;                   // this wave's 4 units-of-64 per plane
  const int sq = lane >> 4, sc = lane & 15;

  for (int kc = 0; kc < K; kc += 64) {
    // ---- stage W chunk (independent of previous compute thanks to barrier below)
#pragma unroll
    for (int jj = 0; jj < 4; ++jj) {
      int j = j0 + jj;
      int g = j >> 1;
      int q = (j & 1) * 4 + sq;
      const unsigned short* srch = Wh + (size_t)(g * 16 + sc) * K + kc + q * 8;
      const unsigned short* srcl = Wl + (size_t)(g * 16 + sc) * K + kc + q * 8;
      __builtin_amdgcn_global_load_lds(
          (const __attribute__((address_space(1))) void*)srch,
          (__attribute__((address_space(3))) void*)((char*)Wlds + j * 1024), 16, 0, 0);
      __builtin_amdgcn_global_load_lds(
          (const __attribute__((address_space(1))) void*)srcl,
          (__attribute__((address_space(3))) void*)((char*)Wlds + 16384 + j * 1024), 16, 0, 0);
    }

    // ---- A fragments for both k-subchunks (overlap with staging latency)
    short8 ah[2][2], al[2][2];
    if (MODE == 0) {
#pragma unroll
      for (int t2 = 0; t2 < 2; ++t2) {
        const float* p = Af32 + (size_t)row[t2] * K + kc + quad * 8;
#pragma unroll
        for (int ks = 0; ks < 2; ++ks) {
          float4 va = *(const float4*)(p + ks * 32);
          float4 vb = *(const float4*)(p + ks * 32 + 4);
          float f[8] = {va.x, va.y, va.z, va.w, vb.x, vb.y, vb.z, vb.w};
#pragma unroll
          for (int j = 0; j < 8; ++j) {
            unsigned short h, l;
            split1(f[j] * dsc[t2], h, l);
            ah[t2][ks][j] = (short)h; al[t2][ks][j] = (short)l;
          }
        }
      }
    } else {
#pragma unroll
      for (int t2 = 0; t2 < 2; ++t2) {
        size_t base = (size_t)row[t2] * K + kc + quad * 8;
#pragma unroll
        for (int ks = 0; ks < 2; ++ks) {
          ah[t2][ks] = *(const short8*)(Ah + base + ks * 32);
          al[t2][ks] = *(const short8*)(Al + base + ks * 32);
        }
      }
    }

    __syncthreads();                       // staging complete, LDS valid

#pragma unroll
    for (int ks = 0; ks < 2; ++ks) {
#pragma unroll
      for (int nt = 0; nt < 4; ++nt) {
        int u = ((wc * 4 + nt) * 8 + ks * 4 + quad) * 16 + col;
        short8 bh = Wlds[u];
        short8 bl = Wlds[1024 + u];
        acc[0][nt] = __builtin_amdgcn_mfma_f32_16x16x32_bf16(ah[0][ks], bh, acc[0][nt], 0, 0, 0);
        acc[0][nt] = __builtin_amdgcn_mfma_f32_16x16x32_bf16(al[0][ks], bh, acc[0][nt], 0, 0, 0);
        acc[0][nt] = __builtin_amdgcn_mfma_f32_16x16x32_bf16(ah[0][ks], bl, acc[0][nt], 0, 0, 0);
        acc[1][nt] = __builtin_amdgcn_mfma_f32_16x16x32_bf16(ah[1][ks], bh, acc[1][nt], 0, 0, 0);
        acc[1][nt] = __builtin_amdgcn_mfma_f32_16x16x32_bf16(al[1][ks], bh, acc[1][nt], 0, 0, 0);
        acc[1][nt] = __builtin_amdgcn_mfma_f32_16x16x32_bf16(ah[1][ks], bl, acc[1][nt], 0, 0, 0);
      }
    }
    __syncthreads();                       // compute done, LDS reusable
  }

#pragma unroll
  for (int mt = 0; mt < 2; ++mt)
#pragma unroll
    for (int r = 0; r < 4; ++r) {
      int m = m_base + mt * 16 + quad * 4 + r;
      if (m < M) {
#pragma unroll
        for (int nt = 0; nt < 4; ++nt)
          C[(size_t)m * NFEAT + wc * 64 + nt * 16 + col] = acc[mt][nt][r];
      }
    }
}

// ---------------- Aggregation ----------------
// m rows already carry dis[src]; out[i] = relu(dis[i]*(sum_{s->i} m[s] + m[i]) + b).
// Half-wave (32 lanes, float4) per node; 4-deep unroll -> 8 gathers in flight/wave.
// MODE 0: write next-layer input = dis[i]*out as bf16 hi/lo.  MODE 1: fp32 out.

template<int MODE>
__global__ __launch_bounds__(256)
void agg_kernel(const float* __restrict__ m, const int* __restrict__ row_ptr,
                const int* __restrict__ csr_src, const float* __restrict__ dis,
                const float* __restrict__ bias,
                unsigned int* __restrict__ out_h, unsigned int* __restrict__ out_l,
                float* __restrict__ out_f, int Nn) {
  int t = threadIdx.x;
  int w = t >> 6, lane = t & 63;
  int sub = lane >> 5, l = lane & 31;
  int i = blockIdx.x * 8 + w * 2 + sub;
  if (i >= Nn) return;
  const float4* m4 = (const float4*)m;
  float4 acc = m4[(size_t)i * 32 + l];             // self-loop term
  int e0 = row_ptr[i], e1 = row_ptr[i + 1];
  int e = e0;
  for (; e + 4 <= e1; e += 4) {
    int s0 = csr_src[e], s1 = csr_src[e + 1], s2 = csr_src[e + 2], s3 = csr_src[e + 3];
    float4 v0 = m4[(size_t)s0 * 32 + l];
    float4 v1 = m4[(size_t)s1 * 32 + l];
    float4 v2 = m4[(size_t)s2 * 32 + l];
    float4 v3 = m4[(size_t)s3 * 32 + l];
    acc.x += (v0.x + v1.x) + (v2.x + v3.x);
    acc.y += (v0.y + v1.y) + (v2.y + v3.y);
    acc.z += (v0.z + v1.z) + (v2.z + v3.z);
    acc.w += (v0.w + v1.w) + (v2.w + v3.w);
  }
  for (; e < e1; ++e) {
    int s = csr_src[e];
    float4 v = m4[(size_t)s * 32 + l];
    acc.x += v.x; acc.y += v.y; acc.z += v.z; acc.w += v.w;
  }
  float di = dis[i];
  float4 b = ((const float4*)bias)[l];
  float r0 = fmaxf(fmaf(di, acc.x, b.x), 0.f);
  float r1 = fmaxf(fmaf(di, acc.y, b.y), 0.f);
  float r2 = fmaxf(fmaf(di, acc.z, b.z), 0.f);
  float r3 = fmaxf(fmaf(di, acc.w, b.w), 0.f);
  if (MODE == 0) {
    unsigned short h0, l0, h1, l1, h2, l2, h3, l3;
    split1(di * r0, h0, l0);
    split1(di * r1, h1, l1);
    split1(di * r2, h2, l2);
    split1(di * r3, h3, l3);
    uint2 ph = make_uint2((unsigned int)h0 | ((unsigned int)h1 << 16),
                          (unsigned int)h2 | ((unsigned int)h3 << 16));
    uint2 pl = make_uint2((unsigned int)l0 | ((unsigned int)l1 << 16),
                          (unsigned int)l2 | ((unsigned int)l3 << 16));
    ((uint2*)out_h)[(size_t)i * 32 + l] = ph;
    ((uint2*)out_l)[(size_t)i * 32 + l] = pl;
  } else {
    ((float4*)out_f)[(size_t)i * 32 + l] = make_float4(r0, r1, r2, r3);
  }
}

// ---------------- Prototype head via MFMA ----------------

__global__ __launch_bounds__(256)
void proto_mfma(const float* __restrict__ emb,
                const unsigned short* __restrict__ Ph, const unsigned short* __restrict__ Pl,
                const float* __restrict__ pn, const float* __restrict__ lastw,
                float* __restrict__ out_logits, float* __restrict__ out_probs,
                float* __restrict__ out_dist, int Nn) {
  __shared__ float simS[64][65];
  int t = threadIdx.x;
  int w = t >> 6, lane = t & 63;
  int col = lane & 15, quad = lane >> 4;
  int m0 = blockIdx.x * 64 + w * 16;
  int row = m0 + col;
  int r0 = row < Nn ? row : Nn - 1;

  floatx4 acc[4];
#pragma unroll
  for (int nt = 0; nt < 4; ++nt) acc[nt] = floatx4{0.f, 0.f, 0.f, 0.f};

  float en = 0.f;
  const float* ap = emb + (size_t)r0 * 128 + quad * 8;
#pragma unroll
  for (int kc = 0; kc < 4; ++kc) {
    float4 va = *(const float4*)(ap + kc * 32);
    float4 vb = *(const float4*)(ap + kc * 32 + 4);
    float f[8] = {va.x, va.y, va.z, va.w, vb.x, vb.y, vb.z, vb.w};
    short8 ah, al;
#pragma unroll
    for (int j = 0; j < 8; ++j) {
      unsigned short h, l;
      split1(f[j], h, l);
      ah[j] = (short)h; al[j] = (short)l;
      en = fmaf(f[j], f[j], en);
    }
#pragma unroll
    for (int nt = 0; nt < 4; ++nt) {
      const unsigned short* bp = Ph + (size_t)(nt * 16 + col) * 128 + kc * 32 + quad * 8;
      const unsigned short* bq = Pl + (size_t)(nt * 16 + col) * 128 + kc * 32 + quad * 8;
      short8 bh = *(const short8*)bp;
      short8 bl = *(const short8*)bq;
      acc[nt] = __builtin_amdgcn_mfma_f32_16x16x32_bf16(ah, bh, acc[nt], 0, 0, 0);
      acc[nt] = __builtin_amdgcn_mfma_f32_16x16x32_bf16(al, bh, acc[nt], 0, 0, 0);
      acc[nt] = __builtin_amdgcn_mfma_f32_16x16x32_bf16(ah, bl, acc[nt], 0, 0, 0);
    }
  }
  en += __shfl_xor(en, 16);
  en += __shfl_xor(en, 32);

  float pnv[4];
#pragma unroll
  for (int nt = 0; nt < 4; ++nt) pnv[nt] = pn[nt * 16 + col];

#pragma unroll
  for (int r = 0; r < 4; ++r) {
    int node = m0 + quad * 4 + r;
    float enr = __shfl(en, quad * 4 + r);
    bool valid = node < Nn;
#pragma unroll
    for (int nt = 0; nt < 4; ++nt) {
      int p = nt * 16 + col;
      float d = enr - 2.f * acc[nt][r] + pnv[nt];
      float sim = (p < NPROTO) ? logf((d + 1.0f) / (d + 1e-4f)) : 0.f;
      simS[w * 16 + quad * 4 + r][p] = sim;
      if (valid && p < NPROTO) out_dist[(size_t)node * NPROTO + p] = d;
    }
  }
  __syncthreads();

  if (t < 64) {
    int node = blockIdx.x * 64 + t;
    if (node < Nn) {
      float sims[NPROTO];
#pragma unroll
      for (int p = 0; p < NPROTO; ++p) sims[p] = simS[t][p];
      float lg[NCLS];
      float mx = -1e30f;
#pragma unroll
      for (int c = 0; c < NCLS; ++c) {
        float s = 0.f;
#pragma unroll
        for (int p = 0; p < NPROTO; ++p) s = fmaf(sims[p], lastw[c * NPROTO + p], s);
        lg[c] = s;
        mx = fmaxf(mx, s);
      }
      float ss = 0.f;
#pragma unroll
      for (int c = 0; c < NCLS; ++c) ss += expf(lg[c] - mx);
      float inv = 1.f / ss;
#pragma unroll
      for (int c = 0; c < NCLS; ++c) {
        out_logits[(size_t)node * NCLS + c] = lg[c];
        out_probs[(size_t)node * NCLS + c] = expf(lg[c] - mx) * inv;
      }
    }
  }
}

// ---------------- launcher ----------------

extern "C" void kernel_launch(void* const* d_in, const int* in_sizes, int n_in,
                              void* d_out, int out_size, void* d_ws, size_t ws_size,
                              hipStream_t stream) {
  const float* x    = (const float*)d_in[0];
  const int*  eidx  = (const int*)d_in[1];
  const float* W1   = (const float*)d_in[2];
  const float* b1   = (const float*)d_in[3];
  const float* W2   = (const float*)d_in[4];
  const float* b2   = (const float*)d_in[5];
  const float* W3   = (const float*)d_in[6];
  const float* b3   = (const float*)d_in[7];
  const float* prot = (const float*)d_in[8];
  const float* lastw= (const float*)d_in[9];

  const int Nn = in_sizes[0] / 512;       // 50000
  const int E  = in_sizes[1] / 2;         // 640000
  const int K1 = 512;
  const int* esrc = eidx;
  const int* edst = eidx + E;

  float* out        = (float*)d_out;
  float* out_logits = out;
  float* out_probs  = out + (size_t)Nn * NCLS;
  float* out_emb    = out + (size_t)Nn * 2 * NCLS;
  float* out_dist   = out_emb + (size_t)Nn * NFEAT;

  // workspace layout
  float* mbuf  = (float*)d_ws;                              // N*128 fp32
  unsigned int* hh = (unsigned int*)(mbuf + (size_t)Nn * NFEAT);
  unsigned int* hl = hh + (size_t)Nn * 64;
  unsigned short* W1h = (unsigned short*)(hl + (size_t)Nn * 64);   // 128*512
  unsigned short* W1l = W1h + 128 * 512;
  unsigned short* W2h = W1l + 128 * 512;                            // 128*128
  unsigned short* W2l = W2h + 128 * 128;
  unsigned short* W3h = W2l + 128 * 128;
  unsigned short* W3l = W3h + 128 * 128;
  unsigned short* Ph  = W3l + 128 * 128;                            // 64*128
  unsigned short* Pl  = Ph + 64 * 128;
  float* pn    = (float*)(Pl + 64 * 128);                   // 64
  int* cnt     = (int*)(pn + 64);                           // N
  float* dis   = (float*)(cnt + Nn);                        // N
  int* row_ptr = (int*)(dis + Nn);                          // N+1
  int* cursor  = row_ptr + Nn + 1;                          // N
  int* csr_src = cursor + Nn;                               // E

  hipMemsetAsync(cnt, 0, Nn * sizeof(int), stream);
  hipMemsetAsync(cursor, 0, Nn * sizeof(int), stream);
  count_kernel<<<(E + 255) / 256, 256, 0, stream>>>(edst, cnt, E);
  scan_kernel<<<1, 1024, 0, stream>>>(cnt, row_ptr, Nn);
  dis_kernel<<<(Nn + 255) / 256, 256, 0, stream>>>(cnt, dis, Nn);
  fill_kernel<<<(E + 255) / 256, 256, 0, stream>>>(esrc, edst, row_ptr, cursor, csr_src, E);

  wconv_kernel<<<(128 * 512 + 255) / 256, 256, 0, stream>>>(W1, W1h, W1l, 128 * 512);
  wconv_kernel<<<(128 * 128 + 255) / 256, 256, 0, stream>>>(W2, W2h, W2l, 128 * 128);
  wconv_kernel<<<(128 * 128 + 255) / 256, 256, 0, stream>>>(W3, W3h, W3l, 128 * 128);
  psplit_kernel<<<1, 128, 0, stream>>>(prot, Ph, Pl, pn);

  int gblocks = (Nn + 63) / 64;
  int ablocks = (Nn + 7) / 8;
  // layer 1: m = (dis . x) @ W1^T
  gemm_v2<0><<<gblocks, 256, 0, stream>>>(x, nullptr, nullptr, dis, W1h, W1l, mbuf, Nn, K1);
  agg_kernel<0><<<ablocks, 256, 0, stream>>>(mbuf, row_ptr, csr_src, dis, b1, hh, hl, nullptr, Nn);
  // layer 2
  gemm_v2<1><<<gblocks, 256, 0, stream>>>(nullptr, (const unsigned short*)hh,
                                          (const unsigned short*)hl, dis, W2h, W2l, mbuf, Nn, NFEAT);
  agg_kernel<0><<<ablocks, 256, 0, stream>>>(mbuf, row_ptr, csr_src, dis, b2, hh, hl, nullptr, Nn);
  // layer 3 -> emb fp32 into d_out
  gemm_v2<1><<<gblocks, 256, 0, stream>>>(nullptr, (const unsigned short*)hh,
                                          (const unsigned short*)hl, dis, W3h, W3l, mbuf, Nn, NFEAT);
  agg_kernel<1><<<ablocks, 256, 0, stream>>>(mbuf, row_ptr, csr_src, dis, b3, nullptr, nullptr, out_emb, Nn);

  proto_mfma<<<(Nn + 63) / 64, 256, 0, stream>>>(out_emb, Ph, Pl, pn, lastw,
                                                 out_logits, out_probs, out_dist, Nn);
}

// Round 5
// 601.691 us; speedup vs baseline: 1.3078x; 1.0023x over previous
//
#include <hip/hip_runtime.h>
#include <cstdint>
#include <cstddef>

#define NFEAT 128
#define NPROTO 50
#define NCLS 10

typedef __attribute__((ext_vector_type(8))) short short8;    // 8 x bf16
typedef __attribute__((ext_vector_type(4))) float floatx4;

// ---------------- CSR build ----------------

__global__ __launch_bounds__(256) void count_kernel(const int* __restrict__ dst,
                                                    int* __restrict__ cnt, int E) {
  int e = blockIdx.x * 256 + threadIdx.x;
  if (e < E) atomicAdd(&cnt[dst[e]], 1);
}

__global__ __launch_bounds__(1024) void scan_kernel(const int* __restrict__ cnt,
                                                    int* __restrict__ row_ptr, int Nn) {
  __shared__ int sums[1024];
  int t = threadIdx.x;
  int CH = (Nn + 1023) >> 10;
  int lo = t * CH, hi = min(lo + CH, Nn);
  int s = 0;
  for (int i = lo; i < hi; ++i) s += cnt[i];
  sums[t] = s;
  __syncthreads();
  for (int off = 1; off < 1024; off <<= 1) {
    int v = sums[t];
    int add = (t >= off) ? sums[t - off] : 0;
    __syncthreads();
    sums[t] = v + add;
    __syncthreads();
  }
  int run = (t == 0) ? 0 : sums[t - 1];
  for (int i = lo; i < hi; ++i) { row_ptr[i] = run; run += cnt[i]; }
  if (t == 1023) row_ptr[Nn] = sums[1023];
}

__global__ __launch_bounds__(256) void dis_kernel(const int* __restrict__ cnt,
                                                  float* __restrict__ dis, int Nn) {
  int i = blockIdx.x * 256 + threadIdx.x;
  if (i < Nn) dis[i] = 1.0f / sqrtf((float)(cnt[i] + 1));  // +1: self-loop
}

__global__ __launch_bounds__(256) void fill_kernel(const int* __restrict__ src,
                                                   const int* __restrict__ dst,
                                                   const int* __restrict__ row_ptr,
                                                   int* __restrict__ cursor,
                                                   int* __restrict__ csr_src, int E) {
  int e = blockIdx.x * 256 + threadIdx.x;
  if (e < E) {
    int d = dst[e];
    int pos = atomicAdd(&cursor[d], 1);
    csr_src[row_ptr[d] + pos] = src[e];
  }
}

// ---------------- fp32 -> bf16 hi/lo split ----------------

__device__ __forceinline__ void split1(float v, unsigned short& h, unsigned short& l) {
  unsigned int b = __float_as_uint(v);
  h = (unsigned short)(b >> 16);
  float r = v - __uint_as_float(b & 0xFFFF0000u);
  l = (unsigned short)(__float_as_uint(r) >> 16);
}

__global__ __launch_bounds__(256) void wconv_kernel(const float* __restrict__ W,
                                                    unsigned short* __restrict__ Wh,
                                                    unsigned short* __restrict__ Wl, int n) {
  int i = blockIdx.x * 256 + threadIdx.x;
  if (i < n) {
    unsigned short h, l;
    split1(W[i], h, l);
    Wh[i] = h; Wl[i] = l;
  }
}

// protos: split to bf16 hi/lo padded to 64 rows, plus squared norms
__global__ __launch_bounds__(128)
void psplit_kernel(const float* __restrict__ proto, unsigned short* __restrict__ Ph,
                   unsigned short* __restrict__ Pl, float* __restrict__ pn) {
  int t = threadIdx.x;
  for (int idx = t; idx < 64 * 128; idx += 128) {
    int p = idx >> 7;
    float v = (p < NPROTO) ? proto[p * 128 + (idx & 127)] : 0.f;
    unsigned short h, l;
    split1(v, h, l);
    Ph[idx] = h; Pl[idx] = l;
  }
  if (t < 64) {
    float s = 0.f;
    if (t < NPROTO)
      for (int f = 0; f < 128; ++f) { float v = proto[t * 128 + f]; s += v * v; }
    pn[t] = s;
  }
}

// ---------------- MFMA GEMM v3: C[M,128] = A[M,K] @ W[128,K]^T ----------------
// Block: 128 rows x 128 cols, 4 waves 2x2, wave = 64 rows (4 m-tiles) x 64 cols
// (4 n-tiles). K processed in 128-wide segments; per segment the full 128x128
// W hi+lo sub-matrix (64 KB) is staged into LDS fragment-linear via
// global_load_lds(16B) and ALL A fragments (512 B/lane) are preloaded before
// one barrier. 192 MFMA per wave per segment vs 32 ds_read_b128 (6:1).
// LDS layout: unit(plane,g,q,c) at plane*2048 + g*256 + q*16 + c,
//   g = col-tile (0..7), q = k-octet (0..15), c = col-in-tile (0..15).
// MODE 0: A fp32, rows scaled by dis[], split in-register (layer 1).
// MODE 1: A pre-split bf16 hi/lo (layers 2/3).

template<int MODE>
__global__ __launch_bounds__(256)
void gemm_v3(const float* __restrict__ Af32,
             const unsigned short* __restrict__ Ah, const unsigned short* __restrict__ Al,
             const float* __restrict__ dis,
             const unsigned short* __restrict__ Wh, const unsigned short* __restrict__ Wl,
             float* __restrict__ C, int M, int K) {
  __shared__ short8 Wlds[4096];            // 64 KB: [2 planes][2048 units]
  int t = threadIdx.x;
  int w = t >> 6, lane = t & 63;
  int col = lane & 15, quad = lane >> 4;
  int wr = w >> 1, wc = w & 1;
  int rowbase = blockIdx.x * 128 + wr * 64;

  floatx4 acc[4][4];                       // [t2][nt]
#pragma unroll
  for (int a = 0; a < 4; ++a)
#pragma unroll
    for (int b = 0; b < 4; ++b) acc[a][b] = floatx4{0.f, 0.f, 0.f, 0.f};

  int row[4];
  float dsc[4];
#pragma unroll
  for (int t2 = 0; t2 < 4; ++t2) {
    int r = rowbase + t2 * 16 + col;
    row[t2] = r < M ? r : M - 1;
    if (MODE == 0) dsc[t2] = dis[row[t2]];
  }

  const int nseg = K >> 7;
  for (int seg = 0; seg < nseg; ++seg) {
    const int kbase = seg << 7;

    // ---- stage W segment hi+lo (64 KB) ----
#pragma unroll
    for (int i = 0; i < 8; ++i) {
      int u = t + i * 256;                 // unit index within plane
      int g = u >> 8, q = (u >> 4) & 15, c = u & 15;
      size_t off = (size_t)(g * 16 + c) * K + kbase + q * 8;
      char* ldsb = (char*)Wlds + (size_t)(i * 256 + w * 64) * 16;
      __builtin_amdgcn_global_load_lds(
          (const __attribute__((address_space(1))) void*)(Wh + off),
          (__attribute__((address_space(3))) void*)ldsb, 16, 0, 0);
      __builtin_amdgcn_global_load_lds(
          (const __attribute__((address_space(1))) void*)(Wl + off),
          (__attribute__((address_space(3))) void*)(ldsb + 32768), 16, 0, 0);
    }

    // ---- preload A fragments for the whole segment (overlaps staging) ----
    short8 ah[4][4], al[4][4];             // [t2][ck]
    if (MODE == 0) {
#pragma unroll
      for (int t2 = 0; t2 < 4; ++t2) {
        const float* p = Af32 + (size_t)row[t2] * K + kbase + quad * 8;
#pragma unroll
        for (int ck = 0; ck < 4; ++ck) {
          float4 va = *(const float4*)(p + ck * 32);
          float4 vb = *(const float4*)(p + ck * 32 + 4);
          float f[8] = {va.x, va.y, va.z, va.w, vb.x, vb.y, vb.z, vb.w};
#pragma unroll
          for (int j = 0; j < 8; ++j) {
            unsigned short h, l;
            split1(f[j] * dsc[t2], h, l);
            ah[t2][ck][j] = (short)h; al[t2][ck][j] = (short)l;
          }
        }
      }
    } else {
#pragma unroll
      for (int t2 = 0; t2 < 4; ++t2) {
        size_t base = (size_t)row[t2] * K + kbase + quad * 8;
#pragma unroll
        for (int ck = 0; ck < 4; ++ck) {
          ah[t2][ck] = *(const short8*)(Ah + base + ck * 32);
          al[t2][ck] = *(const short8*)(Al + base + ck * 32);
        }
      }
    }

    __syncthreads();                       // staging drained, LDS valid

#pragma unroll
    for (int ck = 0; ck < 4; ++ck) {
#pragma unroll
      for (int nt = 0; nt < 4; ++nt) {
        int idx = (wc * 4 + nt) * 256 + (ck * 4 + quad) * 16 + col;
        short8 bh = Wlds[idx];
        short8 bl = Wlds[2048 + idx];
#pragma unroll
        for (int t2 = 0; t2 < 4; ++t2) {
          acc[t2][nt] = __builtin_amdgcn_mfma_f32_16x16x32_bf16(ah[t2][ck], bh, acc[t2][nt], 0, 0, 0);
          acc[t2][nt] = __builtin_amdgcn_mfma_f32_16x16x32_bf16(al[t2][ck], bh, acc[t2][nt], 0, 0, 0);
          acc[t2][nt] = __builtin_amdgcn_mfma_f32_16x16x32_bf16(ah[t2][ck], bl, acc[t2][nt], 0, 0, 0);
        }
      }
    }
    if (seg + 1 < nseg) __syncthreads();   // LDS reuse safety
  }

#pragma unroll
  for (int t2 = 0; t2 < 4; ++t2)
#pragma unroll
    for (int r = 0; r < 4; ++r) {
      int m = rowbase + t2 * 16 + quad * 4 + r;
      if (m < M) {
#pragma unroll
        for (int nt = 0; nt < 4; ++nt)
          C[(size_t)m * NFEAT + wc * 64 + nt * 16 + col] = acc[t2][nt][r];
      }
    }
}

// ---------------- Aggregation ----------------
// m rows already carry dis[src]; out[i] = relu(dis[i]*(sum_{s->i} m[s] + m[i]) + b).
// Half-wave (32 lanes, float4) per node; 4-deep unroll -> 8 gathers in flight/wave.
// MODE 0: write next-layer input = dis[i]*out as bf16 hi/lo.  MODE 1: fp32 out.

template<int MODE>
__global__ __launch_bounds__(256)
void agg_kernel(const float* __restrict__ m, const int* __restrict__ row_ptr,
                const int* __restrict__ csr_src, const float* __restrict__ dis,
                const float* __restrict__ bias,
                unsigned int* __restrict__ out_h, unsigned int* __restrict__ out_l,
                float* __restrict__ out_f, int Nn) {
  int t = threadIdx.x;
  int w = t >> 6, lane = t & 63;
  int sub = lane >> 5, l = lane & 31;
  int i = blockIdx.x * 8 + w * 2 + sub;
  if (i >= Nn) return;
  const float4* m4 = (const float4*)m;
  float4 acc = m4[(size_t)i * 32 + l];             // self-loop term
  int e0 = row_ptr[i], e1 = row_ptr[i + 1];
  int e = e0;
  for (; e + 4 <= e1; e += 4) {
    int s0 = csr_src[e], s1 = csr_src[e + 1], s2 = csr_src[e + 2], s3 = csr_src[e + 3];
    float4 v0 = m4[(size_t)s0 * 32 + l];
    float4 v1 = m4[(size_t)s1 * 32 + l];
    float4 v2 = m4[(size_t)s2 * 32 + l];
    float4 v3 = m4[(size_t)s3 * 32 + l];
    acc.x += (v0.x + v1.x) + (v2.x + v3.x);
    acc.y += (v0.y + v1.y) + (v2.y + v3.y);
    acc.z += (v0.z + v1.z) + (v2.z + v3.z);
    acc.w += (v0.w + v1.w) + (v2.w + v3.w);
  }
  for (; e < e1; ++e) {
    int s = csr_src[e];
    float4 v = m4[(size_t)s * 32 + l];
    acc.x += v.x; acc.y += v.y; acc.z += v.z; acc.w += v.w;
  }
  float di = dis[i];
  float4 b = ((const float4*)bias)[l];
  float r0 = fmaxf(fmaf(di, acc.x, b.x), 0.f);
  float r1 = fmaxf(fmaf(di, acc.y, b.y), 0.f);
  float r2 = fmaxf(fmaf(di, acc.z, b.z), 0.f);
  float r3 = fmaxf(fmaf(di, acc.w, b.w), 0.f);
  if (MODE == 0) {
    unsigned short h0, l0, h1, l1, h2, l2, h3, l3;
    split1(di * r0, h0, l0);
    split1(di * r1, h1, l1);
    split1(di * r2, h2, l2);
    split1(di * r3, h3, l3);
    uint2 ph = make_uint2((unsigned int)h0 | ((unsigned int)h1 << 16),
                          (unsigned int)h2 | ((unsigned int)h3 << 16));
    uint2 pl = make_uint2((unsigned int)l0 | ((unsigned int)l1 << 16),
                          (unsigned int)l2 | ((unsigned int)l3 << 16));
    ((uint2*)out_h)[(size_t)i * 32 + l] = ph;
    ((uint2*)out_l)[(size_t)i * 32 + l] = pl;
  } else {
    ((float4*)out_f)[(size_t)i * 32 + l] = make_float4(r0, r1, r2, r3);
  }
}

// ---------------- Prototype head via MFMA ----------------

__global__ __launch_bounds__(256)
void proto_mfma(const float* __restrict__ emb,
                const unsigned short* __restrict__ Ph, const unsigned short* __restrict__ Pl,
                const float* __restrict__ pn, const float* __restrict__ lastw,
                float* __restrict__ out_logits, float* __restrict__ out_probs,
                float* __restrict__ out_dist, int Nn) {
  __shared__ float simS[64][65];
  int t = threadIdx.x;
  int w = t >> 6, lane = t & 63;
  int col = lane & 15, quad = lane >> 4;
  int m0 = blockIdx.x * 64 + w * 16;
  int row = m0 + col;
  int r0 = row < Nn ? row : Nn - 1;

  floatx4 acc[4];
#pragma unroll
  for (int nt = 0; nt < 4; ++nt) acc[nt] = floatx4{0.f, 0.f, 0.f, 0.f};

  float en = 0.f;
  const float* ap = emb + (size_t)r0 * 128 + quad * 8;
#pragma unroll
  for (int kc = 0; kc < 4; ++kc) {
    float4 va = *(const float4*)(ap + kc * 32);
    float4 vb = *(const float4*)(ap + kc * 32 + 4);
    float f[8] = {va.x, va.y, va.z, va.w, vb.x, vb.y, vb.z, vb.w};
    short8 ah, al;
#pragma unroll
    for (int j = 0; j < 8; ++j) {
      unsigned short h, l;
      split1(f[j], h, l);
      ah[j] = (short)h; al[j] = (short)l;
      en = fmaf(f[j], f[j], en);
    }
#pragma unroll
    for (int nt = 0; nt < 4; ++nt) {
      const unsigned short* bp = Ph + (size_t)(nt * 16 + col) * 128 + kc * 32 + quad * 8;
      const unsigned short* bq = Pl + (size_t)(nt * 16 + col) * 128 + kc * 32 + quad * 8;
      short8 bh = *(const short8*)bp;
      short8 bl = *(const short8*)bq;
      acc[nt] = __builtin_amdgcn_mfma_f32_16x16x32_bf16(ah, bh, acc[nt], 0, 0, 0);
      acc[nt] = __builtin_amdgcn_mfma_f32_16x16x32_bf16(al, bh, acc[nt], 0, 0, 0);
      acc[nt] = __builtin_amdgcn_mfma_f32_16x16x32_bf16(ah, bl, acc[nt], 0, 0, 0);
    }
  }
  en += __shfl_xor(en, 16);
  en += __shfl_xor(en, 32);

  float pnv[4];
#pragma unroll
  for (int nt = 0; nt < 4; ++nt) pnv[nt] = pn[nt * 16 + col];

#pragma unroll
  for (int r = 0; r < 4; ++r) {
    int node = m0 + quad * 4 + r;
    float enr = __shfl(en, quad * 4 + r);
    bool valid = node < Nn;
#pragma unroll
    for (int nt = 0; nt < 4; ++nt) {
      int p = nt * 16 + col;
      float d = enr - 2.f * acc[nt][r] + pnv[nt];
      float sim = (p < NPROTO) ? logf((d + 1.0f) / (d + 1e-4f)) : 0.f;
      simS[w * 16 + quad * 4 + r][p] = sim;
      if (valid && p < NPROTO) out_dist[(size_t)node * NPROTO + p] = d;
    }
  }
  __syncthreads();

  if (t < 64) {
    int node = blockIdx.x * 64 + t;
    if (node < Nn) {
      float sims[NPROTO];
#pragma unroll
      for (int p = 0; p < NPROTO; ++p) sims[p] = simS[t][p];
      float lg[NCLS];
      float mx = -1e30f;
#pragma unroll
      for (int c = 0; c < NCLS; ++c) {
        float s = 0.f;
#pragma unroll
        for (int p = 0; p < NPROTO; ++p) s = fmaf(sims[p], lastw[c * NPROTO + p], s);
        lg[c] = s;
        mx = fmaxf(mx, s);
      }
      float ss = 0.f;
#pragma unroll
      for (int c = 0; c < NCLS; ++c) ss += expf(lg[c] - mx);
      float inv = 1.f / ss;
#pragma unroll
      for (int c = 0; c < NCLS; ++c) {
        out_logits[(size_t)node * NCLS + c] = lg[c];
        out_probs[(size_t)node * NCLS + c] = expf(lg[c] - mx) * inv;
      }
    }
  }
}

// ---------------- launcher ----------------

extern "C" void kernel_launch(void* const* d_in, const int* in_sizes, int n_in,
                              void* d_out, int out_size, void* d_ws, size_t ws_size,
                              hipStream_t stream) {
  const float* x    = (const float*)d_in[0];
  const int*  eidx  = (const int*)d_in[1];
  const float* W1   = (const float*)d_in[2];
  const float* b1   = (const float*)d_in[3];
  const float* W2   = (const float*)d_in[4];
  const float* b2   = (const float*)d_in[5];
  const float* W3   = (const float*)d_in[6];
  const float* b3   = (const float*)d_in[7];
  const float* prot = (const float*)d_in[8];
  const float* lastw= (const float*)d_in[9];

  const int Nn = in_sizes[0] / 512;       // 50000
  const int E  = in_sizes[1] / 2;         // 640000
  const int K1 = 512;
  const int* esrc = eidx;
  const int* edst = eidx + E;

  float* out        = (float*)d_out;
  float* out_logits = out;
  float* out_probs  = out + (size_t)Nn * NCLS;
  float* out_emb    = out + (size_t)Nn * 2 * NCLS;
  float* out_dist   = out_emb + (size_t)Nn * NFEAT;

  // workspace layout
  float* mbuf  = (float*)d_ws;                              // N*128 fp32
  unsigned int* hh = (unsigned int*)(mbuf + (size_t)Nn * NFEAT);
  unsigned int* hl = hh + (size_t)Nn * 64;
  unsigned short* W1h = (unsigned short*)(hl + (size_t)Nn * 64);   // 128*512
  unsigned short* W1l = W1h + 128 * 512;
  unsigned short* W2h = W1l + 128 * 512;                            // 128*128
  unsigned short* W2l = W2h + 128 * 128;
  unsigned short* W3h = W2l + 128 * 128;
  unsigned short* W3l = W3h + 128 * 128;
  unsigned short* Ph  = W3l + 128 * 128;                            // 64*128
  unsigned short* Pl  = Ph + 64 * 128;
  float* pn    = (float*)(Pl + 64 * 128);                   // 64
  int* cnt     = (int*)(pn + 64);                           // N
  float* dis   = (float*)(cnt + Nn);                        // N
  int* row_ptr = (int*)(dis + Nn);                          // N+1
  int* cursor  = row_ptr + Nn + 1;                          // N
  int* csr_src = cursor + Nn;                               // E

  hipMemsetAsync(cnt, 0, Nn * sizeof(int), stream);
  hipMemsetAsync(cursor, 0, Nn * sizeof(int), stream);
  count_kernel<<<(E + 255) / 256, 256, 0, stream>>>(edst, cnt, E);
  scan_kernel<<<1, 1024, 0, stream>>>(cnt, row_ptr, Nn);
  dis_kernel<<<(Nn + 255) / 256, 256, 0, stream>>>(cnt, dis, Nn);
  fill_kernel<<<(E + 255) / 256, 256, 0, stream>>>(esrc, edst, row_ptr, cursor, csr_src, E);

  wconv_kernel<<<(128 * 512 + 255) / 256, 256, 0, stream>>>(W1, W1h, W1l, 128 * 512);
  wconv_kernel<<<(128 * 128 + 255) / 256, 256, 0, stream>>>(W2, W2h, W2l, 128 * 128);
  wconv_kernel<<<(128 * 128 + 255) / 256, 256, 0, stream>>>(W3, W3h, W3l, 128 * 128);
  psplit_kernel<<<1, 128, 0, stream>>>(prot, Ph, Pl, pn);

  int gblocks = (Nn + 127) / 128;
  int ablocks = (Nn + 7) / 8;
  // layer 1: m = (dis . x) @ W1^T
  gemm_v3<0><<<gblocks, 256, 0, stream>>>(x, nullptr, nullptr, dis, W1h, W1l, mbuf, Nn, K1);
  agg_kernel<0><<<ablocks, 256, 0, stream>>>(mbuf, row_ptr, csr_src, dis, b1, hh, hl, nullptr, Nn);
  // layer 2
  gemm_v3<1><<<gblocks, 256, 0, stream>>>(nullptr, (const unsigned short*)hh,
                                          (const unsigned short*)hl, dis, W2h, W2l, mbuf, Nn, NFEAT);
  agg_kernel<0><<<ablocks, 256, 0, stream>>>(mbuf, row_ptr, csr_src, dis, b2, hh, hl, nullptr, Nn);
  // layer 3 -> emb fp32 into d_out
  gemm_v3<1><<<gblocks, 256, 0, stream>>>(nullptr, (const unsigned short*)hh,
                                          (const unsigned short*)hl, dis, W3h, W3l, mbuf, Nn, NFEAT);
  agg_kernel<1><<<ablocks, 256, 0, stream>>>(mbuf, row_ptr, csr_src, dis, b3, nullptr, nullptr, out_emb, Nn);

  proto_mfma<<<(Nn + 63) / 64, 256, 0, stream>>>(out_emb, Ph, Pl, pn, lastw,
                                                 out_logits, out_probs, out_dist, Nn);
}